// Round 1
// baseline (943.498 us; speedup 1.0000x reference)
//
#include <hip/hip_runtime.h>

#define T_    1024
#define H_    2048
#define NH_   16
#define NKV_  4
#define HD_   128
#define E_    16
#define I_    768
#define QKVN  3072

typedef __attribute__((ext_vector_type(8))) short  short8;
typedef __attribute__((ext_vector_type(4))) float  f32x4;

#define BM  128
#define BN  128
#define BK  32
#define BKP 40   // padded LDS K-stride (bf16 elems): 80B rows -> 16B aligned, 2-way banks

__device__ inline unsigned short f2bf(float f) {
  unsigned u = __builtin_bit_cast(unsigned, f);
  return (unsigned short)((u + 0x7fffu + ((u >> 16) & 1u)) >> 16);
}
__device__ inline float bf2f(unsigned short h) {
  unsigned u = ((unsigned)h) << 16;
  return __builtin_bit_cast(float, u);
}

__device__ inline float blk_sum(float v, float* lds) {
#pragma unroll
  for (int o = 32; o; o >>= 1) v += __shfl_down(v, o);
  int w = threadIdx.x >> 6;
  __syncthreads();
  if ((threadIdx.x & 63) == 0) lds[w] = v;
  __syncthreads();
  float s = lds[0];
  int nw = blockDim.x >> 6;
  for (int i = 1; i < nw; ++i) s += lds[i];
  return s;
}
__device__ inline float blk_max(float v, float* lds) {
#pragma unroll
  for (int o = 32; o; o >>= 1) v = fmaxf(v, __shfl_down(v, o));
  int w = threadIdx.x >> 6;
  __syncthreads();
  if ((threadIdx.x & 63) == 0) lds[w] = v;
  __syncthreads();
  float s = lds[0];
  int nw = blockDim.x >> 6;
  for (int i = 1; i < nw; ++i) s = fmaxf(s, lds[i]);
  return s;
}

// ---- GEMM tile helpers (128x128x32, 4 waves, each wave 64x64 via 4x4 16x16 frags) ----

// Stage bf16 rows (A, or B already laid out [N][K]) -> lds[row][k], optional row gather.
__device__ inline void stage_rows(unsigned short* lds, const unsigned short* A, size_t rstride,
                                  int row0, int k0, const int* gather, int gmax) {
  int tid = threadIdx.x;
#pragma unroll
  for (int u = tid; u < 512; u += 256) {
    int row = u >> 2, kg = (u & 3) * 8;
    const unsigned short* src;
    if (gather) {
      int tk = (row < gmax) ? gather[row] : 0;
      src = A + (size_t)tk * rstride + k0 + kg;
    } else {
      src = A + (size_t)(row0 + row) * rstride + k0 + kg;
    }
    *(uint4*)(lds + row * BKP + kg) = *(const uint4*)src;
  }
}

// Stage fp32 [K][N] row-major -> lds[n][k] bf16 (transpose + convert).
__device__ inline void stage_f32T(unsigned short* lds, const float* B, int ldb, int k0, int n0) {
  int tid = threadIdx.x;
#pragma unroll
  for (int u = tid; u < 512; u += 256) {
    int n = u & 127, kg = (u >> 7) * 8;
    const float* src = B + (size_t)(k0 + kg) * ldb + n0 + n;
    unsigned w0 = (unsigned)f2bf(src[0])            | ((unsigned)f2bf(src[(size_t)ldb])     << 16);
    unsigned w1 = (unsigned)f2bf(src[(size_t)2*ldb]) | ((unsigned)f2bf(src[(size_t)3*ldb]) << 16);
    unsigned w2 = (unsigned)f2bf(src[(size_t)4*ldb]) | ((unsigned)f2bf(src[(size_t)5*ldb]) << 16);
    unsigned w3 = (unsigned)f2bf(src[(size_t)6*ldb]) | ((unsigned)f2bf(src[(size_t)7*ldb]) << 16);
    *(uint4*)(lds + n * BKP + kg) = make_uint4(w0, w1, w2, w3);
  }
}

__device__ inline void mma_step(const unsigned short* As, const unsigned short* Bs, f32x4 acc[4][4]) {
  int lane = threadIdx.x & 63;
  int wv = threadIdx.x >> 6;
  int wr = wv >> 1, wc = wv & 1;
  int kk = (lane >> 4) * 8, rr = lane & 15;
  short8 aF[4], bF[4];
#pragma unroll
  for (int m = 0; m < 4; ++m)
    aF[m] = *(const short8*)(As + (wr * 64 + m * 16 + rr) * BKP + kk);
#pragma unroll
  for (int n = 0; n < 4; ++n)
    bF[n] = *(const short8*)(Bs + (wc * 64 + n * 16 + rr) * BKP + kk);
#pragma unroll
  for (int m = 0; m < 4; ++m)
#pragma unroll
    for (int n = 0; n < 4; ++n)
      acc[m][n] = __builtin_amdgcn_mfma_f32_16x16x32_bf16(aF[m], bF[n], acc[m][n], 0, 0, 0);
}

#define ZERO_ACC(acc) do { \
  _Pragma("unroll") for (int m_ = 0; m_ < 4; ++m_) \
  _Pragma("unroll") for (int n_ = 0; n_ < 4; ++n_) acc[m_][n_] = (f32x4){0.f, 0.f, 0.f, 0.f}; \
} while (0)

// ---- kernels ----

__global__ __launch_bounds__(256) void k_rms1(const float* x, const float* w, unsigned short* out) {
  __shared__ float lds[4];
  int t = blockIdx.x, tid = threadIdx.x;
  float v[8]; float ss = 0.f;
#pragma unroll
  for (int i = 0; i < 8; ++i) { v[i] = x[(size_t)t * H_ + tid + 256 * i]; ss += v[i] * v[i]; }
  ss = blk_sum(ss, lds);
  float inv = rsqrtf(ss * (1.f / H_) + 1e-6f);
#pragma unroll
  for (int i = 0; i < 8; ++i)
    out[(size_t)t * H_ + tid + 256 * i] = f2bf(v[i] * inv * w[tid + 256 * i]);
}

__global__ __launch_bounds__(256) void k_rms2(const float* x, const float* w,
                                              float* outf, unsigned short* outb) {
  __shared__ float lds[4];
  int t = blockIdx.x, tid = threadIdx.x;
  float v[8]; float ss = 0.f;
#pragma unroll
  for (int i = 0; i < 8; ++i) { v[i] = x[(size_t)t * H_ + tid + 256 * i]; ss += v[i] * v[i]; }
  ss = blk_sum(ss, lds);
  float inv = rsqrtf(ss * (1.f / H_) + 1e-6f);
#pragma unroll
  for (int i = 0; i < 8; ++i) {
    float r = v[i] * inv * w[tid + 256 * i];
    outf[(size_t)t * H_ + tid + 256 * i] = r;
    outb[(size_t)t * H_ + tid + 256 * i] = f2bf(r);
  }
}

__global__ __launch_bounds__(256) void k_qkv(const unsigned short* h1, const float* wqkv, float* qkv) {
  __shared__ __align__(16) unsigned short As[BM * BKP];
  __shared__ __align__(16) unsigned short Bs[BN * BKP];
  int bn = blockIdx.x, bm = blockIdx.y;
  f32x4 acc[4][4]; ZERO_ACC(acc);
  for (int kt = 0; kt < H_ / BK; ++kt) {
    __syncthreads();
    stage_rows(As, h1, H_, bm * 128, kt * BK, nullptr, 0);
    stage_f32T(Bs, wqkv, QKVN, kt * BK, bn * 128);
    __syncthreads();
    mma_step(As, Bs, acc);
  }
  int lane = threadIdx.x & 63, wv = threadIdx.x >> 6;
  int wr = wv >> 1, wc = wv & 1;
#pragma unroll
  for (int m = 0; m < 4; ++m)
#pragma unroll
    for (int n = 0; n < 4; ++n) {
      f32x4 a = acc[m][n];
#pragma unroll
      for (int r = 0; r < 4; ++r) {
        int row = wr * 64 + m * 16 + (lane >> 4) * 4 + r;
        int col = wc * 64 + n * 16 + (lane & 15);
        qkv[(size_t)(bm * 128 + row) * QKVN + bn * 128 + col] = a[r];
      }
    }
}

__global__ __launch_bounds__(256) void k_qkrope(const float* qkv, const int* pos,
                                                const float* wq, const float* wk,
                                                unsigned short* q, unsigned short* kk,
                                                unsigned short* vT) {
  __shared__ float cs[64], sn[64];
  int t = blockIdx.x, tid = threadIdx.x, lane = tid & 63, w = tid >> 6;
  if (tid < 64) {
    float fr = expf(-((float)tid / 64.f) * 9.210340371976184f);  // 10000^(-d/64)
    float ang = (float)pos[t] * fr;
    float s_, c_; sincosf(ang, &s_, &c_);
    cs[tid] = c_; sn[tid] = s_;
  }
  __syncthreads();
  const float* row = qkv + (size_t)t * QKVN;
  for (int h = w; h < NH_; h += 4) {
    float x1 = row[h * 128 + lane], x2 = row[h * 128 + 64 + lane];
    float ss = x1 * x1 + x2 * x2;
#pragma unroll
    for (int o = 32; o; o >>= 1) ss += __shfl_down(ss, o);
    ss = __shfl(ss, 0);
    float inv = rsqrtf(ss * (1.f / HD_) + 1e-6f);
    float n1 = x1 * inv * wq[lane], n2 = x2 * inv * wq[64 + lane];
    float o1 = n1 * cs[lane] - n2 * sn[lane];
    float o2 = n2 * cs[lane] + n1 * sn[lane];
    q[(size_t)t * (NH_ * HD_) + h * 128 + lane] = f2bf(o1);
    q[(size_t)t * (NH_ * HD_) + h * 128 + 64 + lane] = f2bf(o2);
  }
  if (w < NKV_) {
    int h = w;
    float x1 = row[2048 + h * 128 + lane], x2 = row[2048 + h * 128 + 64 + lane];
    float ss = x1 * x1 + x2 * x2;
#pragma unroll
    for (int o = 32; o; o >>= 1) ss += __shfl_down(ss, o);
    ss = __shfl(ss, 0);
    float inv = rsqrtf(ss * (1.f / HD_) + 1e-6f);
    float n1 = x1 * inv * wk[lane], n2 = x2 * inv * wk[64 + lane];
    float o1 = n1 * cs[lane] - n2 * sn[lane];
    float o2 = n2 * cs[lane] + n1 * sn[lane];
    kk[((size_t)h * T_ + t) * HD_ + lane] = f2bf(o1);
    kk[((size_t)h * T_ + t) * HD_ + 64 + lane] = f2bf(o2);
    float v1 = row[2560 + h * 128 + lane], v2 = row[2560 + h * 128 + 64 + lane];
    vT[((size_t)(h * 128 + lane)) * T_ + t] = f2bf(v1);
    vT[((size_t)(h * 128 + 64 + lane)) * T_ + t] = f2bf(v2);
  }
}

__global__ __launch_bounds__(256) void k_scores(const unsigned short* q, const unsigned short* kb,
                                                unsigned short* S) {
  __shared__ __align__(16) unsigned short As[BM * BKP];
  __shared__ __align__(16) unsigned short Bs[BN * BKP];
  int sn = blockIdx.x, qm = blockIdx.y, h = blockIdx.z;
  const unsigned short* Aq = q + h * 128;                 // rows stride NH*HD
  const unsigned short* Bk = kb + (size_t)(h >> 2) * T_ * HD_;
  f32x4 acc[4][4]; ZERO_ACC(acc);
  for (int kt = 0; kt < HD_ / BK; ++kt) {
    __syncthreads();
    stage_rows(As, Aq, NH_ * HD_, qm * 128, kt * BK, nullptr, 0);
    stage_rows(Bs, Bk, HD_, sn * 128, kt * BK, nullptr, 0);
    __syncthreads();
    mma_step(As, Bs, acc);
  }
  int lane = threadIdx.x & 63, wv = threadIdx.x >> 6;
  int wr = wv >> 1, wc = wv & 1;
  const float scale = 0.08838834764831845f;
#pragma unroll
  for (int m = 0; m < 4; ++m)
#pragma unroll
    for (int n = 0; n < 4; ++n) {
      f32x4 a = acc[m][n];
#pragma unroll
      for (int r = 0; r < 4; ++r) {
        int row = wr * 64 + m * 16 + (lane >> 4) * 4 + r;
        int col = wc * 64 + n * 16 + (lane & 15);
        S[((size_t)h * T_ + qm * 128 + row) * T_ + sn * 128 + col] = f2bf(a[r] * scale);
      }
    }
}

__global__ __launch_bounds__(256) void k_softmax(unsigned short* S) {
  __shared__ float lds[4];
  int t = blockIdx.x, h = blockIdx.y, tid = threadIdx.x;
  unsigned short* rowp = S + ((size_t)h * T_ + t) * T_;
  float x[4];
#pragma unroll
  for (int i = 0; i < 4; ++i) x[i] = bf2f(rowp[tid + 256 * i]);
  float m = fmaxf(fmaxf(x[0], x[1]), fmaxf(x[2], x[3]));
  m = blk_max(m, lds);
  float s = 0.f;
#pragma unroll
  for (int i = 0; i < 4; ++i) { x[i] = __expf(x[i] - m); s += x[i]; }
  s = blk_sum(s, lds);
  float inv = 1.f / s;
#pragma unroll
  for (int i = 0; i < 4; ++i) rowp[tid + 256 * i] = f2bf(x[i] * inv);
}

__global__ __launch_bounds__(256) void k_pv(const unsigned short* P, const unsigned short* vT,
                                            unsigned short* ctx) {
  __shared__ __align__(16) unsigned short As[BM * BKP];
  __shared__ __align__(16) unsigned short Bs[BN * BKP];
  int qm = blockIdx.x, h = blockIdx.y;
  const unsigned short* Ap = P + (size_t)h * T_ * T_;
  const unsigned short* Bv = vT + (size_t)(h >> 2) * HD_ * T_;
  f32x4 acc[4][4]; ZERO_ACC(acc);
  for (int kt = 0; kt < T_ / BK; ++kt) {
    __syncthreads();
    stage_rows(As, Ap, T_, qm * 128, kt * BK, nullptr, 0);
    stage_rows(Bs, Bv, T_, 0, kt * BK, nullptr, 0);
    __syncthreads();
    mma_step(As, Bs, acc);
  }
  int lane = threadIdx.x & 63, wv = threadIdx.x >> 6;
  int wr = wv >> 1, wc = wv & 1;
#pragma unroll
  for (int m = 0; m < 4; ++m)
#pragma unroll
    for (int n = 0; n < 4; ++n) {
      f32x4 a = acc[m][n];
#pragma unroll
      for (int r = 0; r < 4; ++r) {
        int row = wr * 64 + m * 16 + (lane >> 4) * 4 + r;
        int col = wc * 64 + n * 16 + (lane & 15);
        ctx[(size_t)(qm * 128 + row) * (NH_ * HD_) + h * 128 + col] = f2bf(a[r]);
      }
    }
}

__global__ __launch_bounds__(256) void k_wo(const unsigned short* ctx, const float* wo,
                                            const float* hs, float* resid) {
  __shared__ __align__(16) unsigned short As[BM * BKP];
  __shared__ __align__(16) unsigned short Bs[BN * BKP];
  int bn = blockIdx.x, bm = blockIdx.y;
  f32x4 acc[4][4]; ZERO_ACC(acc);
  for (int kt = 0; kt < H_ / BK; ++kt) {
    __syncthreads();
    stage_rows(As, ctx, H_, bm * 128, kt * BK, nullptr, 0);
    stage_f32T(Bs, wo, H_, kt * BK, bn * 128);
    __syncthreads();
    mma_step(As, Bs, acc);
  }
  int lane = threadIdx.x & 63, wv = threadIdx.x >> 6;
  int wr = wv >> 1, wc = wv & 1;
#pragma unroll
  for (int m = 0; m < 4; ++m)
#pragma unroll
    for (int n = 0; n < 4; ++n) {
      f32x4 a = acc[m][n];
#pragma unroll
      for (int r = 0; r < 4; ++r) {
        int row = wr * 64 + m * 16 + (lane >> 4) * 4 + r;
        int col = wc * 64 + n * 16 + (lane & 15);
        size_t idx = (size_t)(bm * 128 + row) * H_ + bn * 128 + col;
        resid[idx] = a[r] + hs[idx];
      }
    }
}

__global__ __launch_bounds__(256) void k_router(const float* h2f, const float* wr_,
                                                int* topi, float* topw, int* cnt) {
  __shared__ float xs[H_];
  __shared__ float red[4][16];
  __shared__ float lg[16];
  int t = blockIdx.x, tid = threadIdx.x;
#pragma unroll
  for (int i = 0; i < 8; ++i) xs[tid + 256 * i] = h2f[(size_t)t * H_ + tid + 256 * i];
  __syncthreads();
  int e = tid & 15, p = tid >> 4;
  float s = 0.f;
  int b0 = p * 128;
  for (int i = 0; i < 128; ++i) s += xs[b0 + i] * wr_[(size_t)(b0 + i) * E_ + e];
  s += __shfl_down(s, 32);
  s += __shfl_down(s, 16);
  int lane = tid & 63, w = tid >> 6;
  if (lane < 16) red[w][lane] = s;
  __syncthreads();
  if (tid < 16) lg[tid] = red[0][tid] + red[1][tid] + red[2][tid] + red[3][tid];
  __syncthreads();
  if (tid == 0) {
    float l1 = -1e30f; int e1 = 0;
    for (int i = 0; i < E_; ++i) if (lg[i] > l1) { l1 = lg[i]; e1 = i; }
    float l2 = -1e30f; int e2 = 0;
    for (int i = 0; i < E_; ++i) if (i != e1 && lg[i] > l2) { l2 = lg[i]; e2 = i; }
    float d = __expf(l2 - l1);
    float w1 = 1.f / (1.f + d), w2 = d / (1.f + d);
    topi[2 * t] = e1; topi[2 * t + 1] = e2;
    topw[2 * t] = w1; topw[2 * t + 1] = w2;
    atomicAdd(&cnt[e1], 1);
    atomicAdd(&cnt[e2], 1);
  }
}

__global__ void k_scan(const int* cnt, int* basearr) {
  if (threadIdx.x == 0) {
    int b = 0;
    for (int e = 0; e < E_; ++e) { basearr[e] = b; b += cnt[e]; }
    basearr[E_] = b;
  }
}

__global__ __launch_bounds__(256) void k_assign(const int* topi, const float* topw,
                                                const int* basearr, int* posc,
                                                int* tok, float* wslot) {
  int t = blockIdx.x * 256 + threadIdx.x;
  if (t < T_) {
#pragma unroll
    for (int j = 0; j < 2; ++j) {
      int e = topi[2 * t + j];
      int p = atomicAdd(&posc[e], 1);
      int s = basearr[e] + p;
      tok[s] = t;
      wslot[s] = topw[2 * t + j];
    }
  }
}

__global__ __launch_bounds__(256) void k_gateup(const unsigned short* h2b,
                                                const float* wg, const float* wu,
                                                const int* cnt, const int* basearr, const int* tok,
                                                unsigned short* act) {
  __shared__ __align__(16) unsigned short As[BM * BKP];
  __shared__ __align__(16) unsigned short Bg[BN * BKP];
  __shared__ __align__(16) unsigned short Bu[BN * BKP];
  int e = blockIdx.z;
  int c = cnt[e];
  int mt = blockIdx.y;
  if (mt * 128 >= c) return;
  int basee = basearr[e];
  int gmax = c - mt * 128;
  const int* gat = tok + basee + mt * 128;
  int n0 = blockIdx.x * 128;
  const float* Bgp = wg + (size_t)e * H_ * I_;
  const float* Bup = wu + (size_t)e * H_ * I_;
  f32x4 accg[4][4], accu[4][4]; ZERO_ACC(accg); ZERO_ACC(accu);
  for (int kt = 0; kt < H_ / BK; ++kt) {
    __syncthreads();
    stage_rows(As, h2b, H_, 0, kt * BK, gat, gmax);
    stage_f32T(Bg, Bgp, I_, kt * BK, n0);
    stage_f32T(Bu, Bup, I_, kt * BK, n0);
    __syncthreads();
    mma_step(As, Bg, accg);
    mma_step(As, Bu, accu);
  }
  int lane = threadIdx.x & 63, wv = threadIdx.x >> 6;
  int wr = wv >> 1, wc = wv & 1;
  int slot0 = basee + mt * 128;
#pragma unroll
  for (int m = 0; m < 4; ++m)
#pragma unroll
    for (int n = 0; n < 4; ++n) {
      f32x4 g4 = accg[m][n], u4 = accu[m][n];
#pragma unroll
      for (int r = 0; r < 4; ++r) {
        int row = wr * 64 + m * 16 + (lane >> 4) * 4 + r;
        if (row >= gmax) continue;
        int col = wc * 64 + n * 16 + (lane & 15);
        float g = g4[r], u = u4[r];
        float sg = g / (1.f + __expf(-g));
        act[(size_t)(slot0 + row) * I_ + n0 + col] = f2bf(sg * u);
      }
    }
}

__global__ __launch_bounds__(256) void k_down(const unsigned short* act, const float* wd,
                                              const int* cnt, const int* basearr,
                                              const int* tok, const float* wslot,
                                              float* moe) {
  __shared__ __align__(16) unsigned short As[BM * BKP];
  __shared__ __align__(16) unsigned short Bs[BN * BKP];
  int e = blockIdx.z;
  int c = cnt[e];
  int mt = blockIdx.y;
  if (mt * 128 >= c) return;
  int basee = basearr[e];
  int gmax = c - mt * 128;
  int slot0 = basee + mt * 128;
  int n0 = blockIdx.x * 128;
  const unsigned short* Ap = act + (size_t)slot0 * I_;
  const float* Bp = wd + (size_t)e * I_ * H_;
  f32x4 acc[4][4]; ZERO_ACC(acc);
  for (int kt = 0; kt < I_ / BK; ++kt) {
    __syncthreads();
    stage_rows(As, Ap, I_, 0, kt * BK, nullptr, 0);
    stage_f32T(Bs, Bp, H_, kt * BK, n0);
    __syncthreads();
    mma_step(As, Bs, acc);
  }
  int lane = threadIdx.x & 63, wv = threadIdx.x >> 6;
  int wr = wv >> 1, wc = wv & 1;
#pragma unroll
  for (int m = 0; m < 4; ++m)
#pragma unroll
    for (int n = 0; n < 4; ++n) {
      f32x4 a = acc[m][n];
#pragma unroll
      for (int r = 0; r < 4; ++r) {
        int row = wr * 64 + m * 16 + (lane >> 4) * 4 + r;
        if (row >= gmax) continue;
        int col = wc * 64 + n * 16 + (lane & 15);
        int slot = slot0 + row;
        float wgt = wslot[slot];
        int tk = tok[slot];
        atomicAdd(&moe[(size_t)tk * H_ + n0 + col], a[r] * wgt);
      }
    }
}

extern "C" void kernel_launch(void* const* d_in, const int* in_sizes, int n_in,
                              void* d_out, int out_size, void* d_ws, size_t ws_size,
                              hipStream_t stream) {
  const float* hs    = (const float*)d_in[0];
  const int*   pos   = (const int*)d_in[1];
  const float* wn1   = (const float*)d_in[2];
  const float* wn2   = (const float*)d_in[3];
  const float* wqkv  = (const float*)d_in[4];
  const float* wqn   = (const float*)d_in[5];
  const float* wkn   = (const float*)d_in[6];
  const float* wo    = (const float*)d_in[7];
  const float* wrt   = (const float*)d_in[8];
  const float* wg    = (const float*)d_in[9];
  const float* wu    = (const float*)d_in[10];
  const float* wd    = (const float*)d_in[11];
  float* out = (float*)d_out;
  float* moe_out = out;                       // T*H fp32
  float* resid   = out + (size_t)T_ * H_;     // T*H fp32

  char* ws = (char*)d_ws;
  size_t off = 0;
  auto alloc = [&](size_t bytes) { size_t r = off; off = (off + bytes + 255) & ~(size_t)255; return r; };
  unsigned short* h1   = (unsigned short*)(ws + alloc((size_t)T_ * H_ * 2));
  float*          qkv  = (float*)         (ws + alloc((size_t)T_ * QKVN * 4));
  unsigned short* q    = (unsigned short*)(ws + alloc((size_t)T_ * NH_ * HD_ * 2));
  unsigned short* kb   = (unsigned short*)(ws + alloc((size_t)NKV_ * T_ * HD_ * 2));
  unsigned short* vT   = (unsigned short*)(ws + alloc((size_t)NKV_ * HD_ * T_ * 2));
  unsigned short* S    = (unsigned short*)(ws + alloc((size_t)NH_ * T_ * T_ * 2));
  unsigned short* ctx  = (unsigned short*)(ws + alloc((size_t)T_ * NH_ * HD_ * 2));
  float*          h2f  = (float*)         (ws + alloc((size_t)T_ * H_ * 4));
  unsigned short* h2b  = (unsigned short*)(ws + alloc((size_t)T_ * H_ * 2));
  unsigned short* act  = (unsigned short*)(ws + alloc((size_t)(2 * T_ + 256) * I_ * 2));
  int*            topi = (int*)           (ws + alloc((size_t)T_ * 2 * 4));
  float*          topw = (float*)         (ws + alloc((size_t)T_ * 2 * 4));
  int*            cnt  = (int*)           (ws + alloc(32 * 4));        // cnt[16] + pos[16]
  int*            posc = cnt + 16;
  int*            base = (int*)           (ws + alloc(32 * 4));
  int*            tok  = (int*)           (ws + alloc((size_t)(2 * T_ + 128) * 4));
  float*          wsl  = (float*)         (ws + alloc((size_t)(2 * T_ + 128) * 4));
  (void)ws_size; (void)in_sizes; (void)n_in; (void)out_size;

  hipMemsetAsync(moe_out, 0, (size_t)T_ * H_ * 4, stream);
  hipMemsetAsync(cnt, 0, 32 * 4, stream);

  k_rms1<<<T_, 256, 0, stream>>>(hs, wn1, h1);
  k_qkv<<<dim3(QKVN / 128, T_ / 128), 256, 0, stream>>>(h1, wqkv, qkv);
  k_qkrope<<<T_, 256, 0, stream>>>(qkv, pos, wqn, wkn, q, kb, vT);
  k_scores<<<dim3(T_ / 128, T_ / 128, NH_), 256, 0, stream>>>(q, kb, S);
  k_softmax<<<dim3(T_, NH_), 256, 0, stream>>>(S);
  k_pv<<<dim3(T_ / 128, NH_), 256, 0, stream>>>(S, vT, ctx);
  k_wo<<<dim3(H_ / 128, T_ / 128), 256, 0, stream>>>(ctx, wo, hs, resid);
  k_rms2<<<T_, 256, 0, stream>>>(resid, wn2, h2f, h2b);
  k_router<<<T_, 256, 0, stream>>>(h2f, wrt, topi, topw, cnt);
  k_scan<<<1, 64, 0, stream>>>(cnt, base);
  k_assign<<<4, 256, 0, stream>>>(topi, topw, base, posc, tok, wsl);
  k_gateup<<<dim3(I_ / 128, T_ / 128, E_), 256, 0, stream>>>(h2b, wg, wu, cnt, base, tok, act);
  k_down<<<dim3(H_ / 128, T_ / 128, E_), 256, 0, stream>>>(act, wd, cnt, base, tok, wsl, moe_out);
}

// Round 2
// 498.962 us; speedup vs baseline: 1.8909x; 1.8909x over previous
//
#include <hip/hip_runtime.h>

#define T_    1024
#define H_    2048
#define NH_   16
#define NKV_  4
#define HD_   128
#define E_    16
#define I_    768
#define QKVN  3072

typedef __attribute__((ext_vector_type(8))) short  short8;
typedef __attribute__((ext_vector_type(4))) float  f32x4;
typedef unsigned short u16;

#define BKP 40   // padded LDS K-stride (bf16): 80B rows -> 16B aligned, worst 2-way banks (free)

__device__ inline u16 f2bf(float f) {
  unsigned u = __builtin_bit_cast(unsigned, f);
  return (u16)((u + 0x7fffu + ((u >> 16) & 1u)) >> 16);
}
__device__ inline float bf2f(u16 h) {
  unsigned u = ((unsigned)h) << 16;
  return __builtin_bit_cast(float, u);
}

__device__ inline float blk_sum(float v, float* lds) {
#pragma unroll
  for (int o = 32; o; o >>= 1) v += __shfl_down(v, o);
  int w = threadIdx.x >> 6;
  __syncthreads();
  if ((threadIdx.x & 63) == 0) lds[w] = v;
  __syncthreads();
  float s = lds[0];
  int nw = blockDim.x >> 6;
  for (int i = 1; i < nw; ++i) s += lds[i];
  return s;
}
__device__ inline float blk_max(float v, float* lds) {
#pragma unroll
  for (int o = 32; o; o >>= 1) v = fmaxf(v, __shfl_down(v, o));
  int w = threadIdx.x >> 6;
  __syncthreads();
  if ((threadIdx.x & 63) == 0) lds[w] = v;
  __syncthreads();
  float s = lds[0];
  int nw = blockDim.x >> 6;
  for (int i = 1; i < nw; ++i) s = fmaxf(s, lds[i]);
  return s;
}

// ---------------- GEMM building blocks ----------------
// Tile: BM x 128 x 32 per K-step, 4 waves (2x2), wave tile (BM/2)x64,
// per-wave frags MR x 4 of 16x16x32. Register-prefetch pipeline:
// loop { barrier; regs->LDS; barrier; issue loads(t+1)->regs; mma(t); }

// bf16 rows [rows][stride] -> regs (BM/64 x 16B chunks per thread)
template<int BM, bool GATHER>
__device__ inline void loadA(uint4* r, const u16* A, size_t stride, int row0, int k0,
                             const int* gat_s) {
#pragma unroll
  for (int i = 0; i < BM / 64; ++i) {
    int u = threadIdx.x + 256 * i;
    int row = u >> 2, kg = (u & 3) * 8;
    int grow = GATHER ? gat_s[row] : (row0 + row);
    r[i] = *(const uint4*)(A + (size_t)grow * stride + k0 + kg);
  }
}
template<int BM>
__device__ inline void writeA(u16* lds, const uint4* r) {
#pragma unroll
  for (int i = 0; i < BM / 64; ++i) {
    int u = threadIdx.x + 256 * i;
    int row = u >> 2, kg = (u & 3) * 8;
    *(uint4*)(lds + row * BKP + kg) = r[i];
  }
}

// fp32 [K][N] row-major -> regs (16 floats: 2 chunks x 8 consecutive k)
__device__ inline void loadBf32(float* r, const float* B, int ldb, int k0, int n0) {
#pragma unroll
  for (int i = 0; i < 2; ++i) {
    int u = threadIdx.x + 256 * i;
    int n = u & 127, kg = (u >> 7) * 8;
    const float* src = B + (size_t)(k0 + kg) * ldb + n0 + n;
#pragma unroll
    for (int j = 0; j < 8; ++j) r[i * 8 + j] = src[(size_t)j * ldb];
  }
}
__device__ inline void writeBf32(u16* lds, const float* r) {
#pragma unroll
  for (int i = 0; i < 2; ++i) {
    int u = threadIdx.x + 256 * i;
    int n = u & 127, kg = (u >> 7) * 8;
    uint4 w;
    w.x = (unsigned)f2bf(r[i*8+0]) | ((unsigned)f2bf(r[i*8+1]) << 16);
    w.y = (unsigned)f2bf(r[i*8+2]) | ((unsigned)f2bf(r[i*8+3]) << 16);
    w.z = (unsigned)f2bf(r[i*8+4]) | ((unsigned)f2bf(r[i*8+5]) << 16);
    w.w = (unsigned)f2bf(r[i*8+6]) | ((unsigned)f2bf(r[i*8+7]) << 16);
    *(uint4*)(lds + n * BKP + kg) = w;
  }
}

template<int MR>
__device__ inline void mma_step(const u16* As, const u16* Bs, f32x4 acc[][4]) {
  const int lane = threadIdx.x & 63, wv = threadIdx.x >> 6;
  const int wr = wv >> 1, wc = wv & 1;
  const int kk = (lane >> 4) * 8, rr = lane & 15;
  short8 aF[MR], bF[4];
#pragma unroll
  for (int m = 0; m < MR; ++m)
    aF[m] = *(const short8*)(As + (wr * MR * 16 + m * 16 + rr) * BKP + kk);
#pragma unroll
  for (int n = 0; n < 4; ++n)
    bF[n] = *(const short8*)(Bs + (wc * 64 + n * 16 + rr) * BKP + kk);
#pragma unroll
  for (int m = 0; m < MR; ++m)
#pragma unroll
    for (int n = 0; n < 4; ++n)
      acc[m][n] = __builtin_amdgcn_mfma_f32_16x16x32_bf16(aF[m], bF[n], acc[m][n], 0, 0, 0);
}

#define ZERO_ACC(acc, MR) do { \
  _Pragma("unroll") for (int m_ = 0; m_ < MR; ++m_) \
  _Pragma("unroll") for (int n_ = 0; n_ < 4; ++n_) acc[m_][n_] = (f32x4){0.f,0.f,0.f,0.f}; \
} while (0)

// epilogue index helpers: row within tile / col within 128-tile
#define EPI_ROW(MR, m, r)  (((threadIdx.x >> 6) >> 1) * (MR*16) + (m)*16 + (((threadIdx.x&63) >> 4) * 4) + (r))
#define EPI_COL(n)         ((((threadIdx.x >> 6) & 1) * 64) + (n)*16 + ((threadIdx.x&63) & 15))

// ---------------- kernels ----------------

__global__ __launch_bounds__(256) void k_rms1(const float* x, const float* w, u16* out) {
  __shared__ float lds[4];
  int t = blockIdx.x, tid = threadIdx.x;
  float v[8]; float ss = 0.f;
#pragma unroll
  for (int i = 0; i < 8; ++i) { v[i] = x[(size_t)t * H_ + tid + 256 * i]; ss += v[i] * v[i]; }
  ss = blk_sum(ss, lds);
  float inv = rsqrtf(ss * (1.f / H_) + 1e-6f);
#pragma unroll
  for (int i = 0; i < 8; ++i)
    out[(size_t)t * H_ + tid + 256 * i] = f2bf(v[i] * inv * w[tid + 256 * i]);
}

__global__ __launch_bounds__(256) void k_rms2(const float* x, const float* w,
                                              float* outf, u16* outb) {
  __shared__ float lds[4];
  int t = blockIdx.x, tid = threadIdx.x;
  float v[8]; float ss = 0.f;
#pragma unroll
  for (int i = 0; i < 8; ++i) { v[i] = x[(size_t)t * H_ + tid + 256 * i]; ss += v[i] * v[i]; }
  ss = blk_sum(ss, lds);
  float inv = rsqrtf(ss * (1.f / H_) + 1e-6f);
#pragma unroll
  for (int i = 0; i < 8; ++i) {
    float r = v[i] * inv * w[tid + 256 * i];
    outf[(size_t)t * H_ + tid + 256 * i] = r;
    outb[(size_t)t * H_ + tid + 256 * i] = f2bf(r);
  }
}

__global__ __launch_bounds__(256) void k_qkv(const u16* h1, const float* wqkv, float* qkv) {
  __shared__ __align__(16) u16 As[128 * BKP];
  __shared__ __align__(16) u16 Bs[128 * BKP];
  int bn = blockIdx.x, bm = blockIdx.y;
  f32x4 acc[4][4]; ZERO_ACC(acc, 4);
  uint4 ra[2]; float rb[16];
  loadA<128, false>(ra, h1, H_, bm * 128, 0, nullptr);
  loadBf32(rb, wqkv, QKVN, 0, bn * 128);
  const int NT = H_ / 32;
  for (int kt = 0; kt < NT; ++kt) {
    __syncthreads();
    writeA<128>(As, ra);
    writeBf32(Bs, rb);
    __syncthreads();
    if (kt + 1 < NT) {
      loadA<128, false>(ra, h1, H_, bm * 128, (kt + 1) * 32, nullptr);
      loadBf32(rb, wqkv, QKVN, (kt + 1) * 32, bn * 128);
    }
    mma_step<4>(As, Bs, acc);
  }
#pragma unroll
  for (int m = 0; m < 4; ++m)
#pragma unroll
    for (int n = 0; n < 4; ++n) {
      f32x4 a = acc[m][n];
#pragma unroll
      for (int r = 0; r < 4; ++r)
        qkv[(size_t)(bm * 128 + EPI_ROW(4, m, r)) * QKVN + bn * 128 + EPI_COL(n)] = a[r];
    }
}

__global__ __launch_bounds__(256) void k_qkrope(const float* qkv, const int* pos,
                                                const float* wq, const float* wk,
                                                u16* q, u16* kk, u16* vT) {
  __shared__ float cs[64], sn[64];
  int t = blockIdx.x, tid = threadIdx.x, lane = tid & 63, w = tid >> 6;
  if (tid < 64) {
    float fr = expf(-((float)tid / 64.f) * 9.210340371976184f);  // 10000^(-d/64)
    float ang = (float)pos[t] * fr;
    float s_, c_; sincosf(ang, &s_, &c_);
    cs[tid] = c_; sn[tid] = s_;
  }
  __syncthreads();
  const float* row = qkv + (size_t)t * QKVN;
  for (int h = w; h < NH_; h += 4) {
    float x1 = row[h * 128 + lane], x2 = row[h * 128 + 64 + lane];
    float ss = x1 * x1 + x2 * x2;
#pragma unroll
    for (int o = 32; o; o >>= 1) ss += __shfl_down(ss, o);
    ss = __shfl(ss, 0);
    float inv = rsqrtf(ss * (1.f / HD_) + 1e-6f);
    float n1 = x1 * inv * wq[lane], n2 = x2 * inv * wq[64 + lane];
    float o1 = n1 * cs[lane] - n2 * sn[lane];
    float o2 = n2 * cs[lane] + n1 * sn[lane];
    q[(size_t)t * (NH_ * HD_) + h * 128 + lane] = f2bf(o1);
    q[(size_t)t * (NH_ * HD_) + h * 128 + 64 + lane] = f2bf(o2);
  }
  if (w < NKV_) {
    int h = w;
    float x1 = row[2048 + h * 128 + lane], x2 = row[2048 + h * 128 + 64 + lane];
    float ss = x1 * x1 + x2 * x2;
#pragma unroll
    for (int o = 32; o; o >>= 1) ss += __shfl_down(ss, o);
    ss = __shfl(ss, 0);
    float inv = rsqrtf(ss * (1.f / HD_) + 1e-6f);
    float n1 = x1 * inv * wk[lane], n2 = x2 * inv * wk[64 + lane];
    float o1 = n1 * cs[lane] - n2 * sn[lane];
    float o2 = n2 * cs[lane] + n1 * sn[lane];
    kk[((size_t)h * T_ + t) * HD_ + lane] = f2bf(o1);
    kk[((size_t)h * T_ + t) * HD_ + 64 + lane] = f2bf(o2);
    float v1 = row[2560 + h * 128 + lane], v2 = row[2560 + h * 128 + 64 + lane];
    vT[((size_t)(h * 128 + lane)) * T_ + t] = f2bf(v1);
    vT[((size_t)(h * 128 + 64 + lane)) * T_ + t] = f2bf(v2);
  }
}

__global__ __launch_bounds__(256) void k_scores(const u16* q, const u16* kb, u16* S) {
  __shared__ __align__(16) u16 As[128 * BKP];
  __shared__ __align__(16) u16 Bs[128 * BKP];
  int sn = blockIdx.x, qm = blockIdx.y, h = blockIdx.z;
  const u16* Aq = q + h * 128;
  const u16* Bk = kb + (size_t)(h >> 2) * T_ * HD_;
  f32x4 acc[4][4]; ZERO_ACC(acc, 4);
  uint4 ra[2], rb[2];
  loadA<128, false>(ra, Aq, NH_ * HD_, qm * 128, 0, nullptr);
  loadA<128, false>(rb, Bk, HD_, sn * 128, 0, nullptr);
  const int NT = HD_ / 32;
  for (int kt = 0; kt < NT; ++kt) {
    __syncthreads();
    writeA<128>(As, ra);
    writeA<128>(Bs, rb);
    __syncthreads();
    if (kt + 1 < NT) {
      loadA<128, false>(ra, Aq, NH_ * HD_, qm * 128, (kt + 1) * 32, nullptr);
      loadA<128, false>(rb, Bk, HD_, sn * 128, (kt + 1) * 32, nullptr);
    }
    mma_step<4>(As, Bs, acc);
  }
  const float scale = 0.08838834764831845f;
#pragma unroll
  for (int m = 0; m < 4; ++m)
#pragma unroll
    for (int n = 0; n < 4; ++n) {
      f32x4 a = acc[m][n];
#pragma unroll
      for (int r = 0; r < 4; ++r)
        S[((size_t)h * T_ + qm * 128 + EPI_ROW(4, m, r)) * T_ + sn * 128 + EPI_COL(n)] =
            f2bf(a[r] * scale);
    }
}

__global__ __launch_bounds__(256) void k_softmax(u16* S) {
  __shared__ float lds[4];
  int t = blockIdx.x, h = blockIdx.y, tid = threadIdx.x;
  u16* rowp = S + ((size_t)h * T_ + t) * T_;
  float x[4];
#pragma unroll
  for (int i = 0; i < 4; ++i) x[i] = bf2f(rowp[tid + 256 * i]);
  float m = fmaxf(fmaxf(x[0], x[1]), fmaxf(x[2], x[3]));
  m = blk_max(m, lds);
  float s = 0.f;
#pragma unroll
  for (int i = 0; i < 4; ++i) { x[i] = __expf(x[i] - m); s += x[i]; }
  s = blk_sum(s, lds);
  float inv = 1.f / s;
#pragma unroll
  for (int i = 0; i < 4; ++i) rowp[tid + 256 * i] = f2bf(x[i] * inv);
}

__global__ __launch_bounds__(256) void k_pv(const u16* P, const u16* vT, u16* ctx) {
  __shared__ __align__(16) u16 As[128 * BKP];
  __shared__ __align__(16) u16 Bs[128 * BKP];
  int qm = blockIdx.x, h = blockIdx.y;
  const u16* Ap = P + (size_t)h * T_ * T_;
  const u16* Bv = vT + (size_t)(h >> 2) * HD_ * T_;
  f32x4 acc[4][4]; ZERO_ACC(acc, 4);
  uint4 ra[2], rb[2];
  loadA<128, false>(ra, Ap, T_, qm * 128, 0, nullptr);
  loadA<128, false>(rb, Bv, T_, 0, 0, nullptr);
  const int NT = T_ / 32;
  for (int kt = 0; kt < NT; ++kt) {
    __syncthreads();
    writeA<128>(As, ra);
    writeA<128>(Bs, rb);
    __syncthreads();
    if (kt + 1 < NT) {
      loadA<128, false>(ra, Ap, T_, qm * 128, (kt + 1) * 32, nullptr);
      loadA<128, false>(rb, Bv, T_, 0, (kt + 1) * 32, nullptr);
    }
    mma_step<4>(As, Bs, acc);
  }
#pragma unroll
  for (int m = 0; m < 4; ++m)
#pragma unroll
    for (int n = 0; n < 4; ++n) {
      f32x4 a = acc[m][n];
#pragma unroll
      for (int r = 0; r < 4; ++r)
        ctx[(size_t)(qm * 128 + EPI_ROW(4, m, r)) * (NH_ * HD_) + h * 128 + EPI_COL(n)] =
            f2bf(a[r]);
    }
}

__global__ __launch_bounds__(256) void k_wo(const u16* ctx, const float* wo,
                                            const float* hs, float* resid) {
  __shared__ __align__(16) u16 As[128 * BKP];
  __shared__ __align__(16) u16 Bs[128 * BKP];
  int bn = blockIdx.x, bm = blockIdx.y;
  f32x4 acc[4][4]; ZERO_ACC(acc, 4);
  uint4 ra[2]; float rb[16];
  loadA<128, false>(ra, ctx, H_, bm * 128, 0, nullptr);
  loadBf32(rb, wo, H_, 0, bn * 128);
  const int NT = H_ / 32;
  for (int kt = 0; kt < NT; ++kt) {
    __syncthreads();
    writeA<128>(As, ra);
    writeBf32(Bs, rb);
    __syncthreads();
    if (kt + 1 < NT) {
      loadA<128, false>(ra, ctx, H_, bm * 128, (kt + 1) * 32, nullptr);
      loadBf32(rb, wo, H_, (kt + 1) * 32, bn * 128);
    }
    mma_step<4>(As, Bs, acc);
  }
#pragma unroll
  for (int m = 0; m < 4; ++m)
#pragma unroll
    for (int n = 0; n < 4; ++n) {
      f32x4 a = acc[m][n];
#pragma unroll
      for (int r = 0; r < 4; ++r) {
        size_t idx = (size_t)(bm * 128 + EPI_ROW(4, m, r)) * H_ + bn * 128 + EPI_COL(n);
        resid[idx] = a[r] + hs[idx];
      }
    }
}

__global__ __launch_bounds__(256) void k_router(const float* h2f, const float* wr_,
                                                int* topi, float* topw, int* cnt) {
  __shared__ float xs[H_];
  __shared__ float red[4][16];
  __shared__ float lg[16];
  int t = blockIdx.x, tid = threadIdx.x;
#pragma unroll
  for (int i = 0; i < 8; ++i) xs[tid + 256 * i] = h2f[(size_t)t * H_ + tid + 256 * i];
  __syncthreads();
  int e = tid & 15, p = tid >> 4;
  float s = 0.f;
  int b0 = p * 128;
  for (int i = 0; i < 128; ++i) s += xs[b0 + i] * wr_[(size_t)(b0 + i) * E_ + e];
  s += __shfl_down(s, 32);
  s += __shfl_down(s, 16);
  int lane = tid & 63, w = tid >> 6;
  if (lane < 16) red[w][lane] = s;
  __syncthreads();
  if (tid < 16) lg[tid] = red[0][tid] + red[1][tid] + red[2][tid] + red[3][tid];
  __syncthreads();
  if (tid == 0) {
    float l1 = -1e30f; int e1 = 0;
    for (int i = 0; i < E_; ++i) if (lg[i] > l1) { l1 = lg[i]; e1 = i; }
    float l2 = -1e30f; int e2 = 0;
    for (int i = 0; i < E_; ++i) if (i != e1 && lg[i] > l2) { l2 = lg[i]; e2 = i; }
    float d = __expf(l2 - l1);
    float w1 = 1.f / (1.f + d), w2 = d / (1.f + d);
    topi[2 * t] = e1; topi[2 * t + 1] = e2;
    topw[2 * t] = w1; topw[2 * t + 1] = w2;
    atomicAdd(&cnt[e1], 1);
    atomicAdd(&cnt[e2], 1);
  }
}

__global__ void k_scan(const int* cnt, int* basearr) {
  if (threadIdx.x == 0) {
    int b = 0;
    for (int e = 0; e < E_; ++e) { basearr[e] = b; b += cnt[e]; }
    basearr[E_] = b;
  }
}

__global__ __launch_bounds__(256) void k_assign(const int* topi, const float* topw,
                                                const int* basearr, int* posc,
                                                int* tok, float* wslot) {
  int t = blockIdx.x * 256 + threadIdx.x;
  if (t < T_) {
#pragma unroll
    for (int j = 0; j < 2; ++j) {
      int e = topi[2 * t + j];
      int p = atomicAdd(&posc[e], 1);
      int s = basearr[e] + p;
      tok[s] = t;
      wslot[s] = topw[2 * t + j];
    }
  }
}

// BM=64 tiles: ~192 active blocks. Dual-B (gate+up), fused silu epilogue.
__global__ __launch_bounds__(256) void k_gateup(const u16* h2b,
                                                const float* wg, const float* wu,
                                                const int* cnt, const int* basearr, const int* tok,
                                                u16* act) {
  __shared__ __align__(16) u16 As[64 * BKP];
  __shared__ __align__(16) u16 Bg[128 * BKP];
  __shared__ __align__(16) u16 Bu[128 * BKP];
  __shared__ int gat_s[64];
  int e = blockIdx.z;
  int c = cnt[e];
  int mt = blockIdx.y;
  if (mt * 64 >= c) return;
  int basee = basearr[e];
  int gmax = c - mt * 64;
  int n0 = blockIdx.x * 128;
  int tid = threadIdx.x;
  if (tid < 64) {
    int r = mt * 64 + tid;
    gat_s[tid] = (r < c) ? tok[basee + r] : tok[basee];
  }
  __syncthreads();
  const float* Bgp = wg + (size_t)e * H_ * I_;
  const float* Bup = wu + (size_t)e * H_ * I_;
  f32x4 accg[2][4], accu[2][4]; ZERO_ACC(accg, 2); ZERO_ACC(accu, 2);
  uint4 ra[1]; float rbg[16], rbu[16];
  loadA<64, true>(ra, h2b, H_, 0, 0, gat_s);
  loadBf32(rbg, Bgp, I_, 0, n0);
  loadBf32(rbu, Bup, I_, 0, n0);
  const int NT = H_ / 32;
  for (int kt = 0; kt < NT; ++kt) {
    __syncthreads();
    writeA<64>(As, ra);
    writeBf32(Bg, rbg);
    writeBf32(Bu, rbu);
    __syncthreads();
    if (kt + 1 < NT) {
      loadA<64, true>(ra, h2b, H_, 0, (kt + 1) * 32, gat_s);
      loadBf32(rbg, Bgp, I_, (kt + 1) * 32, n0);
      loadBf32(rbu, Bup, I_, (kt + 1) * 32, n0);
    }
    mma_step<2>(As, Bg, accg);
    mma_step<2>(As, Bu, accu);
  }
  int slot0 = basee + mt * 64;
#pragma unroll
  for (int m = 0; m < 2; ++m)
#pragma unroll
    for (int n = 0; n < 4; ++n) {
      f32x4 g4 = accg[m][n], u4 = accu[m][n];
#pragma unroll
      for (int r = 0; r < 4; ++r) {
        int row = EPI_ROW(2, m, r);
        if (row >= gmax) continue;
        int col = EPI_COL(n);
        float g = g4[r], u = u4[r];
        float sg = g / (1.f + __expf(-g));
        act[(size_t)(slot0 + row) * I_ + n0 + col] = f2bf(sg * u);
      }
    }
}

// BM=64 tiles: ~512 active blocks. Weighted atomic scatter epilogue.
__global__ __launch_bounds__(256) void k_down(const u16* act, const float* wd,
                                              const int* cnt, const int* basearr,
                                              const int* tok, const float* wslot,
                                              float* moe) {
  __shared__ __align__(16) u16 As[64 * BKP];
  __shared__ __align__(16) u16 Bs[128 * BKP];
  int e = blockIdx.z;
  int c = cnt[e];
  int mt = blockIdx.y;
  if (mt * 64 >= c) return;
  int basee = basearr[e];
  int gmax = c - mt * 64;
  int slot0 = basee + mt * 64;
  int n0 = blockIdx.x * 128;
  const u16* Ap = act + (size_t)slot0 * I_;
  const float* Bp = wd + (size_t)e * I_ * H_;
  f32x4 acc[2][4]; ZERO_ACC(acc, 2);
  uint4 ra[1]; float rb[16];
  loadA<64, false>(ra, Ap, I_, 0, 0, nullptr);
  loadBf32(rb, Bp, H_, 0, n0);
  const int NT = I_ / 32;
  for (int kt = 0; kt < NT; ++kt) {
    __syncthreads();
    writeA<64>(As, ra);
    writeBf32(Bs, rb);
    __syncthreads();
    if (kt + 1 < NT) {
      loadA<64, false>(ra, Ap, I_, 0, (kt + 1) * 32, nullptr);
      loadBf32(rb, Bp, H_, (kt + 1) * 32, n0);
    }
    mma_step<2>(As, Bs, acc);
  }
#pragma unroll
  for (int m = 0; m < 2; ++m)
#pragma unroll
    for (int n = 0; n < 4; ++n) {
      f32x4 a = acc[m][n];
#pragma unroll
      for (int r = 0; r < 4; ++r) {
        int row = EPI_ROW(2, m, r);
        if (row >= gmax) continue;
        int col = EPI_COL(n);
        int slot = slot0 + row;
        float wgt = wslot[slot];
        int tk = tok[slot];
        atomicAdd(&moe[(size_t)tk * H_ + n0 + col], a[r] * wgt);
      }
    }
}

extern "C" void kernel_launch(void* const* d_in, const int* in_sizes, int n_in,
                              void* d_out, int out_size, void* d_ws, size_t ws_size,
                              hipStream_t stream) {
  const float* hs    = (const float*)d_in[0];
  const int*   pos   = (const int*)d_in[1];
  const float* wn1   = (const float*)d_in[2];
  const float* wn2   = (const float*)d_in[3];
  const float* wqkv  = (const float*)d_in[4];
  const float* wqn   = (const float*)d_in[5];
  const float* wkn   = (const float*)d_in[6];
  const float* wo    = (const float*)d_in[7];
  const float* wrt   = (const float*)d_in[8];
  const float* wg    = (const float*)d_in[9];
  const float* wu    = (const float*)d_in[10];
  const float* wd    = (const float*)d_in[11];
  float* out = (float*)d_out;
  float* moe_out = out;                       // T*H fp32
  float* resid   = out + (size_t)T_ * H_;     // T*H fp32

  char* ws = (char*)d_ws;
  size_t off = 0;
  auto alloc = [&](size_t bytes) { size_t r = off; off = (off + bytes + 255) & ~(size_t)255; return r; };
  u16*   h1   = (u16*)  (ws + alloc((size_t)T_ * H_ * 2));
  float* qkv  = (float*)(ws + alloc((size_t)T_ * QKVN * 4));
  u16*   q    = (u16*)  (ws + alloc((size_t)T_ * NH_ * HD_ * 2));
  u16*   kb   = (u16*)  (ws + alloc((size_t)NKV_ * T_ * HD_ * 2));
  u16*   vT   = (u16*)  (ws + alloc((size_t)NKV_ * HD_ * T_ * 2));
  u16*   S    = (u16*)  (ws + alloc((size_t)NH_ * T_ * T_ * 2));
  u16*   ctx  = (u16*)  (ws + alloc((size_t)T_ * NH_ * HD_ * 2));
  float* h2f  = (float*)(ws + alloc((size_t)T_ * H_ * 4));
  u16*   h2b  = (u16*)  (ws + alloc((size_t)T_ * H_ * 2));
  u16*   act  = (u16*)  (ws + alloc((size_t)(2 * T_ + 256) * I_ * 2));
  int*   topi = (int*)  (ws + alloc((size_t)T_ * 2 * 4));
  float* topw = (float*)(ws + alloc((size_t)T_ * 2 * 4));
  int*   cnt  = (int*)  (ws + alloc(32 * 4));        // cnt[16] + pos[16]
  int*   posc = cnt + 16;
  int*   base = (int*)  (ws + alloc(32 * 4));
  int*   tok  = (int*)  (ws + alloc((size_t)(2 * T_ + 128) * 4));
  float* wsl  = (float*)(ws + alloc((size_t)(2 * T_ + 128) * 4));
  (void)ws_size; (void)in_sizes; (void)n_in; (void)out_size;

  hipMemsetAsync(moe_out, 0, (size_t)T_ * H_ * 4, stream);
  hipMemsetAsync(cnt, 0, 32 * 4, stream);

  k_rms1<<<T_, 256, 0, stream>>>(hs, wn1, h1);
  k_qkv<<<dim3(QKVN / 128, T_ / 128), 256, 0, stream>>>(h1, wqkv, qkv);
  k_qkrope<<<T_, 256, 0, stream>>>(qkv, pos, wqn, wkn, q, kb, vT);
  k_scores<<<dim3(T_ / 128, T_ / 128, NH_), 256, 0, stream>>>(q, kb, S);
  k_softmax<<<dim3(T_, NH_), 256, 0, stream>>>(S);
  k_pv<<<dim3(T_ / 128, NH_), 256, 0, stream>>>(S, vT, ctx);
  k_wo<<<dim3(H_ / 128, T_ / 128), 256, 0, stream>>>(ctx, wo, hs, resid);
  k_rms2<<<T_, 256, 0, stream>>>(resid, wn2, h2f, h2b);
  k_router<<<T_, 256, 0, stream>>>(h2f, wrt, topi, topw, cnt);
  k_scan<<<1, 64, 0, stream>>>(cnt, base);
  k_assign<<<4, 256, 0, stream>>>(topi, topw, base, posc, tok, wsl);
  k_gateup<<<dim3(I_ / 128, T_ / 64, E_), 256, 0, stream>>>(h2b, wg, wu, cnt, base, tok, act);
  k_down<<<dim3(H_ / 128, T_ / 64, E_), 256, 0, stream>>>(act, wd, cnt, base, tok, wsl, moe_out);
}